// Round 12
// baseline (206.585 us; speedup 1.0000x reference)
//
#include <hip/hip_runtime.h>
#include <cstdint>
#include <cstddef>

#define NNODES 50000
#define NEDGES 800000
#define MEDGES (NEDGES + NNODES)
#define FIN    256
#define HID    96
#define NCLS   32
#define NEG_SLOPE 0.2f

#define NBUCK  391      // ceil(50000/128): 128-node dst ranges
#define BCAP   3072     // per-bucket staging capacity (mean 2176, sigma ~45)

typedef unsigned int uint32;
typedef __attribute__((ext_vector_type(8))) short short8;   // 8 bf16 = 4 VGPR
typedef __attribute__((ext_vector_type(4))) float f32x4;    // MFMA acc

__device__ __forceinline__ ushort bf_round(float f) {
    uint32 u = __float_as_uint(f);
    u += 0x7FFFu + ((u >> 16) & 1u);            // RNE
    return (ushort)(u >> 16);
}
__device__ __forceinline__ uint32 pack_bf16x2(float a, float b) {
    return (uint32)bf_round(a) | ((uint32)bf_round(b) << 16);
}
__device__ __forceinline__ float bf_lo(uint32 u) { return __uint_as_float(u << 16); }
__device__ __forceinline__ float bf_hi(uint32 u) { return __uint_as_float(u & 0xFFFF0000u); }
__device__ __forceinline__ float lrelu(float t) { return (t > 0.f) ? t : NEG_SLOPE * t; }
__device__ __forceinline__ float af(int i) { return __int_as_float(i); }
__device__ __forceinline__ float elu_fast(float t) { return (t > 0.f) ? t : (__expf(t) - 1.f); }

// ---------------- CSR build: bucketed two-pass sort ----------------
// staging entry packed: src (16 bits, 50000<65536) | (dst&127)<<16.

__global__ __launch_bounds__(256) void bucket1_kernel(const int* __restrict__ ei,
                                                      int* __restrict__ gcount,
                                                      int* __restrict__ staging) {
    __shared__ int hist[NBUCK];
    __shared__ int base_sh[NBUCK];
    for (int i = threadIdx.x; i < NBUCK; i += 256) hist[i] = 0;
    __syncthreads();

    int v[8], rk[8], bk[8];
    int e0 = blockIdx.x * 2048;
#pragma unroll
    for (int i = 0; i < 8; ++i) {
        int e = e0 + i * 256 + threadIdx.x;
        if (e < MEDGES) {
            int s, d;
            if (e < NEDGES) { s = ei[e]; d = ei[NEDGES + e]; }
            else            { s = e - NEDGES; d = s; }
            bk[i] = d >> 7;
            v[i]  = s | ((d & 127) << 16);
            rk[i] = atomicAdd(&hist[bk[i]], 1);
        } else bk[i] = -1;
    }
    __syncthreads();
    for (int i = threadIdx.x; i < NBUCK; i += 256) {
        int c = hist[i];
        base_sh[i] = c ? atomicAdd(&gcount[i], c) : 0;
    }
    __syncthreads();
#pragma unroll
    for (int i = 0; i < 8; ++i) {
        if (bk[i] >= 0) {
            int pos = base_sh[bk[i]] + rk[i];
            if (pos < BCAP)
                staging[(size_t)bk[i] * BCAP + pos] = v[i];
        }
    }
}

// One block per bucket. Self-scans gcount for its edge-space base, builds
// rowptr via LDS scan, writes esrc contiguously (L2-local lines).
__global__ __launch_bounds__(256) void bucket2_kernel(const int* __restrict__ staging,
                                                      const int* __restrict__ gcount,
                                                      int* __restrict__ rowptr,
                                                      int* __restrict__ esrc) {
    __shared__ int dcount[128];
    __shared__ int dincl[128];
    __shared__ int dexcl[128];
    __shared__ int fillc[128];
    __shared__ int red_s[256];

    const int b = blockIdx.x;
    const int t = threadIdx.x;

    int pv = 0;
    for (int idx = t; idx < b; idx += 256) pv += gcount[idx];
    red_s[t] = pv;
    __syncthreads();
    for (int off2 = 128; off2; off2 >>= 1) {
        if (t < off2) red_s[t] += red_s[t + off2];
        __syncthreads();
    }
    const int ebase = red_s[0];
    const int cnt   = gcount[b];
    const int node0 = b << 7;
    const int* st   = staging + (size_t)b * BCAP;

    for (int i = t; i < 128; i += 256) { dcount[i] = 0; fillc[i] = 0; }
    __syncthreads();

    for (int i = t; i < cnt; i += 256)
        atomicAdd(&dcount[st[i] >> 16], 1);
    __syncthreads();

    if (t < 128) dincl[t] = dcount[t];
    __syncthreads();
    for (int off = 1; off < 128; off <<= 1) {
        int val = (t >= off && t < 128) ? dincl[t - off] : 0;
        __syncthreads();
        if (t < 128) dincl[t] += val;
        __syncthreads();
    }
    if (t < 128) {
        int excl = dincl[t] - dcount[t];
        dexcl[t] = excl;
        int node = node0 + t;
        if (node < NNODES) rowptr[node] = ebase + excl;
    }
    if (b == NBUCK - 1 && t == 0) rowptr[NNODES] = MEDGES;
    __syncthreads();

    for (int i = t; i < cnt; i += 256) {
        int v = st[i];
        int dd = v >> 16;
        int r = atomicAdd(&fillc[dd], 1);
        esrc[ebase + dexcl[dd] + r] = v & 0xFFFF;
    }
}

// ---------------- W-pack (also zeroes gcount, replacing a memset dispatch) ----------------

__global__ __launch_bounds__(256) void packw_kernel(const float* __restrict__ W1,
                                                    const float* __restrict__ W2,
                                                    ushort* __restrict__ W1p,
                                                    ushort* __restrict__ W2p,
                                                    int* __restrict__ gcount) {
    int stride = gridDim.x * 256;
    for (int idx = blockIdx.x * 256 + threadIdx.x; idx < NBUCK; idx += stride)
        gcount[idx] = 0;
    for (int idx = blockIdx.x * 256 + threadIdx.x; idx < 6 * 8 * 64 * 8; idx += stride) {
        int j     = idx & 7;
        int lane  = (idx >> 3) & 63;
        int kstep = (idx >> 9) & 7;
        int ntile = idx >> 12;
        int k = kstep * 32 + ((lane >> 4) << 3) + j;
        int n = ntile * 16 + (lane & 15);
        W1p[idx] = bf_round(W1[(size_t)k * 96 + n]);
    }
    for (int idx = blockIdx.x * 256 + threadIdx.x; idx < 2 * 3 * 64 * 8; idx += stride) {
        int j     = idx & 7;
        int lane  = (idx >> 3) & 63;
        int kstep = (idx >> 9) % 3;
        int ntile = (idx >> 9) / 3;
        int k = kstep * 32 + ((lane >> 4) << 3) + j;
        int n = ntile * 16 + (lane & 15);
        W2p[idx] = bf_round(W2[(size_t)k * 32 + n]);
    }
}

// ---------------- GEMM1 via MFMA: h1(bf16) = x @ W1 (+ fused alpha dots) ----------------

__global__ __launch_bounds__(256) void gemm1_kernel(const float* __restrict__ x,
                                                    const ushort* __restrict__ W1p,
                                                    const float* __restrict__ a_src,
                                                    const float* __restrict__ a_dst,
                                                    ushort* __restrict__ h1,
                                                    float* __restrict__ as1,
                                                    float* __restrict__ ad1) {
    const int tid  = threadIdx.x;
    const int lane = tid & 63;
    const int wv   = tid >> 6;
    const int m    = lane & 15;
    const int quad = lane >> 4;
    const int node0 = blockIdx.x * 64;

    int arow = node0 + wv * 16 + m;
    if (arow >= NNODES) arow = NNODES - 1;
    const float* xr = x + (size_t)arow * FIN + quad * 8;

    const short8* Wp = (const short8*)W1p;

    f32x4 acc[6];
#pragma unroll
    for (int t = 0; t < 6; ++t) acc[t] = (f32x4){0.f, 0.f, 0.f, 0.f};

#pragma unroll
    for (int ks = 0; ks < 8; ++ks) {
        float4 v0 = *(const float4*)(xr + ks * 32);
        float4 v1 = *(const float4*)(xr + ks * 32 + 4);
        short8 a;
        a[0] = (short)bf_round(v0.x); a[1] = (short)bf_round(v0.y);
        a[2] = (short)bf_round(v0.z); a[3] = (short)bf_round(v0.w);
        a[4] = (short)bf_round(v1.x); a[5] = (short)bf_round(v1.y);
        a[6] = (short)bf_round(v1.z); a[7] = (short)bf_round(v1.w);
#pragma unroll
        for (int t = 0; t < 6; ++t) {
            short8 b = Wp[(t * 8 + ks) * 64 + lane];
            acc[t] = __builtin_amdgcn_mfma_f32_16x16x32_bf16(a, b, acc[t], 0, 0, 0);
        }
    }

    float as_reg[6], ad_reg[6];
#pragma unroll
    for (int t = 0; t < 6; ++t) {
        as_reg[t] = a_src[t * 16 + m];
        ad_reg[t] = a_dst[t * 16 + m];
    }

#pragma unroll
    for (int r = 0; r < 4; ++r) {
        int node = node0 + wv * 16 + quad * 4 + r;
        float ps = 0.f, pd = 0.f;
#pragma unroll
        for (int t = 0; t < 6; ++t) {
            ps += acc[t][r] * as_reg[t];
            pd += acc[t][r] * ad_reg[t];
        }
#pragma unroll
        for (int off = 1; off < 16; off <<= 1) {
            ps += __shfl_xor(ps, off);
            pd += __shfl_xor(pd, off);
        }
        if (node < NNODES) {
            ushort* hp = h1 + (size_t)node * 96 + m;
#pragma unroll
            for (int t = 0; t < 6; ++t) hp[t * 16] = bf_round(acc[t][r]);
            if (m == 0) { as1[node] = ps; ad1[node] = pd; }
        }
    }
}

// ---------------- GEMM2 via MFMA: h2(bf16 packed) = out1(bf16) @ W2 ----------------
// h2b[node*16 + m] packs (feat m, feat m+16) -> 64 B rows for agg32's gather.

__global__ __launch_bounds__(256) void gemm2_kernel(const uint32* __restrict__ y48,
                                                    const ushort* __restrict__ W2p,
                                                    const float* __restrict__ a_src,
                                                    const float* __restrict__ a_dst,
                                                    uint32* __restrict__ h2b,
                                                    float* __restrict__ as2,
                                                    float* __restrict__ ad2) {
    const int tid  = threadIdx.x;
    const int lane = tid & 63;
    const int wv   = tid >> 6;
    const int m    = lane & 15;
    const int quad = lane >> 4;
    const int node0 = blockIdx.x * 64;

    int arow = node0 + wv * 16 + m;
    if (arow >= NNODES) arow = NNODES - 1;
    const short8* Ar = (const short8*)(y48 + (size_t)arow * 48);
    const short8* Wp = (const short8*)W2p;

    f32x4 acc[2];
    acc[0] = (f32x4){0.f, 0.f, 0.f, 0.f};
    acc[1] = (f32x4){0.f, 0.f, 0.f, 0.f};

#pragma unroll
    for (int ks = 0; ks < 3; ++ks) {
        short8 a = Ar[ks * 4 + quad];
#pragma unroll
        for (int t = 0; t < 2; ++t) {
            short8 b = Wp[(t * 3 + ks) * 64 + lane];
            acc[t] = __builtin_amdgcn_mfma_f32_16x16x32_bf16(a, b, acc[t], 0, 0, 0);
        }
    }

    float as_reg[2], ad_reg[2];
#pragma unroll
    for (int t = 0; t < 2; ++t) {
        as_reg[t] = a_src[t * 16 + m];
        ad_reg[t] = a_dst[t * 16 + m];
    }

#pragma unroll
    for (int r = 0; r < 4; ++r) {
        int node = node0 + wv * 16 + quad * 4 + r;
        float ps = 0.f, pd = 0.f;
#pragma unroll
        for (int t = 0; t < 2; ++t) {
            ps += acc[t][r] * as_reg[t];
            pd += acc[t][r] * ad_reg[t];
        }
#pragma unroll
        for (int off = 1; off < 16; off <<= 1) {
            ps += __shfl_xor(ps, off);
            pd += __shfl_xor(pd, off);
        }
        if (node < NNODES) {
            h2b[(size_t)node * 16 + m] = pack_bf16x2(acc[0][r], acc[1][r]);
            if (m == 0) { as2[node] = ps; ad2[node] = pd; }
        }
    }
}

// ---------------- Fused attn + aggregation layer 1: TWO nodes per wave ----------------
// Half-wave per node, 24 active lanes x uint2 = 192B row, lane owns 4 feats.
// sa.x holds PRE-SCALED row offset (s*96) so the gather loop skips the per-lane
// v_mul in the address chain (computed once per edge in the softmax phase).

__global__ __launch_bounds__(256) void agg96_kernel(const ushort* __restrict__ h,
                                                    const float* __restrict__ asrc,
                                                    const float* __restrict__ adst,
                                                    const float* __restrict__ bias,
                                                    const int* __restrict__ rowptr,
                                                    const int* __restrict__ esrc,
                                                    uint32* __restrict__ out1b) {
    __shared__ int2 sa[4][2][32];
    const int wave = threadIdx.x >> 6;
    const int lane = threadIdx.x & 63;
    const int hf   = lane >> 5;
    const int fl32 = lane & 31;
    const int i = blockIdx.x * 8 + wave * 2 + hf;   // 50000 = 8*6250 exact

    const int start = rowptr[i];
    const int deg   = rowptr[i + 1] - start;
    const float ad  = adst[i];
    const int fl    = (fl32 < 24) ? fl32 : 23;

    float acc0 = 0.f, acc1 = 0.f, acc2 = 0.f, acc3 = 0.f;

    if (deg <= 32) {
        bool valid = fl32 < deg;
        int s_reg = valid ? esrc[start + fl32] : 0;
        float e = valid ? lrelu(asrc[s_reg] + ad) : -1e30f;
        float mx = e;
#pragma unroll
        for (int off = 16; off; off >>= 1) mx = fmaxf(mx, __shfl_xor(mx, off));
        float ex = valid ? __expf(e - mx) : 0.f;
        float sum = ex;
#pragma unroll
        for (int off = 16; off; off >>= 1) sum += __shfl_xor(sum, off);
        sa[wave][hf][fl32] = make_int2(s_reg * 96, __float_as_int(ex / sum));

        const int4* sap = (const int4*)&sa[wave][hf][0];

        for (int eb = 0; eb < deg; eb += 8) {
            int4 qa = sap[(eb >> 1) + 0];
            int4 qb = sap[(eb >> 1) + 1];
            int4 qc = sap[(eb >> 1) + 2];
            int4 qd = sap[(eb >> 1) + 3];
            const uint2* r0 = (const uint2*)(h + (size_t)qa.x);
            const uint2* r1 = (const uint2*)(h + (size_t)qa.z);
            const uint2* r2 = (const uint2*)(h + (size_t)qb.x);
            const uint2* r3 = (const uint2*)(h + (size_t)qb.z);
            const uint2* r4 = (const uint2*)(h + (size_t)qc.x);
            const uint2* r5 = (const uint2*)(h + (size_t)qc.z);
            const uint2* r6 = (const uint2*)(h + (size_t)qd.x);
            const uint2* r7 = (const uint2*)(h + (size_t)qd.z);
            uint2 u0 = r0[fl], u1 = r1[fl], u2 = r2[fl], u3 = r3[fl];
            uint2 u4 = r4[fl], u5 = r5[fl], u6 = r6[fl], u7 = r7[fl];
            float a0 = af(qa.y), a1 = af(qa.w), a2 = af(qb.y), a3 = af(qb.w);
            float a4 = af(qc.y), a5 = af(qc.w), a6 = af(qd.y), a7 = af(qd.w);
            acc0 += a0 * bf_lo(u0.x) + a1 * bf_lo(u1.x) + a2 * bf_lo(u2.x) + a3 * bf_lo(u3.x)
                  + a4 * bf_lo(u4.x) + a5 * bf_lo(u5.x) + a6 * bf_lo(u6.x) + a7 * bf_lo(u7.x);
            acc1 += a0 * bf_hi(u0.x) + a1 * bf_hi(u1.x) + a2 * bf_hi(u2.x) + a3 * bf_hi(u3.x)
                  + a4 * bf_hi(u4.x) + a5 * bf_hi(u5.x) + a6 * bf_hi(u6.x) + a7 * bf_hi(u7.x);
            acc2 += a0 * bf_lo(u0.y) + a1 * bf_lo(u1.y) + a2 * bf_lo(u2.y) + a3 * bf_lo(u3.y)
                  + a4 * bf_lo(u4.y) + a5 * bf_lo(u5.y) + a6 * bf_lo(u6.y) + a7 * bf_lo(u7.y);
            acc3 += a0 * bf_hi(u0.y) + a1 * bf_hi(u1.y) + a2 * bf_hi(u2.y) + a3 * bf_hi(u3.y)
                  + a4 * bf_hi(u4.y) + a5 * bf_hi(u5.y) + a6 * bf_hi(u6.y) + a7 * bf_hi(u7.y);
        }
    } else {
        float mx = -1e30f;
        for (int p = start + fl32; p < start + deg; p += 32)
            mx = fmaxf(mx, lrelu(asrc[esrc[p]] + ad));
#pragma unroll
        for (int off = 16; off; off >>= 1) mx = fmaxf(mx, __shfl_xor(mx, off));
        float sum = 0.f;
        for (int p = start + fl32; p < start + deg; p += 32)
            sum += __expf(lrelu(asrc[esrc[p]] + ad) - mx);
#pragma unroll
        for (int off = 16; off; off >>= 1) sum += __shfl_xor(sum, off);
        float inv = 1.f / sum;
        for (int e = 0; e < deg; ++e) {
            int s = esrc[start + e];
            float a = __expf(lrelu(asrc[s] + ad) - mx) * inv;
            uint2 u = ((const uint2*)(h + (size_t)s * 96))[fl];
            acc0 += a * bf_lo(u.x);
            acc1 += a * bf_hi(u.x);
            acc2 += a * bf_lo(u.y);
            acc3 += a * bf_hi(u.y);
        }
    }

    if (fl32 < 24) {
        float v0 = elu_fast(acc0 + bias[4 * fl32 + 0]);
        float v1 = elu_fast(acc1 + bias[4 * fl32 + 1]);
        float v2 = elu_fast(acc2 + bias[4 * fl32 + 2]);
        float v3 = elu_fast(acc3 + bias[4 * fl32 + 3]);
        uint2 o;
        o.x = pack_bf16x2(v0, v1);
        o.y = pack_bf16x2(v2, v3);
        *(uint2*)(out1b + (size_t)i * 48 + 2 * fl32) = o;
    }
}

// ---------------- Fused attn + aggregation layer 2: TWO nodes per wave ----------------
// Half-wave per node; 4 groups x 8 lanes read 64 B h2b rows via dwordx2.
// sa.x pre-scaled (s*16). h2b uint32 index m holds feats (m, m+16).

__global__ __launch_bounds__(256) void agg32_kernel(const uint32* __restrict__ h2b,
                                                    const float* __restrict__ asrc,
                                                    const float* __restrict__ adst,
                                                    const float* __restrict__ bias,
                                                    const int* __restrict__ rowptr,
                                                    const int* __restrict__ esrc,
                                                    float* __restrict__ out) {
    __shared__ int2 sa[4][2][32];
    const int wave = threadIdx.x >> 6;
    const int lane = threadIdx.x & 63;
    const int hf   = lane >> 5;
    const int fl32 = lane & 31;
    const int i = blockIdx.x * 8 + wave * 2 + hf;   // 6250 blocks exact

    const int start = rowptr[i];
    const int deg   = rowptr[i + 1] - start;
    const float ad  = adst[i];
    const int g  = fl32 >> 3;        // edge group 0..3 within half
    const int fl = fl32 & 7;         // uint2 index within row

    float acc[4];
#pragma unroll
    for (int j = 0; j < 4; ++j) acc[j] = 0.f;

    if (deg <= 32) {
        bool valid = fl32 < deg;
        int s_reg = valid ? esrc[start + fl32] : 0;
        float e = valid ? lrelu(asrc[s_reg] + ad) : -1e30f;
        float mx = e;
#pragma unroll
        for (int off = 16; off; off >>= 1) mx = fmaxf(mx, __shfl_xor(mx, off));
        float ex = valid ? __expf(e - mx) : 0.f;
        float sum = ex;
#pragma unroll
        for (int off = 16; off; off >>= 1) sum += __shfl_xor(sum, off);
        sa[wave][hf][fl32] = make_int2(s_reg * 16, __float_as_int(ex / sum));

#pragma unroll 2
        for (int eb = 0; eb < deg; eb += 4) {
            int e0 = eb + g;
            int2 q = sa[wave][hf][(e0 < 32) ? e0 : 31];
            float a = (e0 < deg) ? af(q.y) : 0.f;
            const uint2* hr = (const uint2*)(h2b + (size_t)q.x);
            uint2 u = hr[fl];
            acc[0] = fmaf(a, bf_lo(u.x), acc[0]);   // feat 2fl
            acc[1] = fmaf(a, bf_hi(u.x), acc[1]);   // feat 2fl+16
            acc[2] = fmaf(a, bf_lo(u.y), acc[2]);   // feat 2fl+1
            acc[3] = fmaf(a, bf_hi(u.y), acc[3]);   // feat 2fl+17
        }
    } else {
        float mx = -1e30f;
        for (int p = start + fl32; p < start + deg; p += 32)
            mx = fmaxf(mx, lrelu(asrc[esrc[p]] + ad));
#pragma unroll
        for (int off = 16; off; off >>= 1) mx = fmaxf(mx, __shfl_xor(mx, off));
        float sum = 0.f;
        for (int p = start + fl32; p < start + deg; p += 32)
            sum += __expf(lrelu(asrc[esrc[p]] + ad) - mx);
#pragma unroll
        for (int off = 16; off; off >>= 1) sum += __shfl_xor(sum, off);
        float inv = 1.f / sum;
        for (int p = start + g; p < start + deg; p += 4) {
            int s = esrc[p];
            float a = __expf(lrelu(asrc[s] + ad) - mx) * inv;
            const uint2* hr = (const uint2*)(h2b + (size_t)s * 16);
            uint2 u = hr[fl];
            acc[0] = fmaf(a, bf_lo(u.x), acc[0]);
            acc[1] = fmaf(a, bf_hi(u.x), acc[1]);
            acc[2] = fmaf(a, bf_lo(u.y), acc[2]);
            acc[3] = fmaf(a, bf_hi(u.y), acc[3]);
        }
    }

#pragma unroll
    for (int j = 0; j < 4; ++j) {
        acc[j] += __shfl_xor(acc[j], 8);
        acc[j] += __shfl_xor(acc[j], 16);
    }

    float z0 = acc[0] + bias[2 * fl];
    float z1 = acc[1] + bias[2 * fl + 16];
    float z2 = acc[2] + bias[2 * fl + 1];
    float z3 = acc[3] + bias[2 * fl + 17];
    float m2 = fmaxf(fmaxf(z0, z1), fmaxf(z2, z3));
#pragma unroll
    for (int off = 4; off; off >>= 1) m2 = fmaxf(m2, __shfl_xor(m2, off));
    float s2 = __expf(z0 - m2) + __expf(z1 - m2) + __expf(z2 - m2) + __expf(z3 - m2);
#pragma unroll
    for (int off = 4; off; off >>= 1) s2 += __shfl_xor(s2, off);
    float ls = m2 + __logf(s2);
    if (fl32 < 8) {
        float* op = out + (size_t)i * 32;
        op[2 * fl]      = z0 - ls;
        op[2 * fl + 16] = z1 - ls;
        op[2 * fl + 1]  = z2 - ls;
        op[2 * fl + 17] = z3 - ls;
    }
}

// ---------------- launch ----------------

extern "C" void kernel_launch(void* const* d_in, const int* in_sizes, int n_in,
                              void* d_out, int out_size, void* d_ws, size_t ws_size,
                              hipStream_t stream) {
    const float* x   = (const float*)d_in[0];
    const int*   ei  = (const int*)d_in[1];
    const float* W1  = (const float*)d_in[2];
    const float* a1s = (const float*)d_in[3];
    const float* a1d = (const float*)d_in[4];
    const float* b1  = (const float*)d_in[5];
    const float* W2  = (const float*)d_in[6];
    const float* a2s = (const float*)d_in[7];
    const float* a2d = (const float*)d_in[8];
    const float* b2  = (const float*)d_in[9];
    float* out = (float*)d_out;

    size_t off = 0;
    auto alloc = [&](size_t bytes) {
        void* p = (char*)d_ws + off;
        off += (bytes + 255) & ~(size_t)255;
        return p;
    };
    ushort* h1    = (ushort*)alloc((size_t)NNODES * HID * 2);   // bf16, 9.6 MB
    uint32* out1b = (uint32*)alloc((size_t)NNODES * 48 * 4);    // bf16x2, 9.6 MB
    int*  staging = (int*)alloc((size_t)NBUCK * BCAP * 4);      // 4.8 MB
    float* as1    = (float*)alloc((size_t)NNODES * 4);
    float* ad1    = (float*)alloc((size_t)NNODES * 4);
    float* as2    = (float*)alloc((size_t)NNODES * 4);
    float* ad2    = (float*)alloc((size_t)NNODES * 4);
    int*   rowptr = (int*)alloc((size_t)(NNODES + 1) * 4);
    int*   esrc   = (int*)alloc((size_t)MEDGES * 4);
    ushort* W1p   = (ushort*)alloc((size_t)6 * 8 * 64 * 8 * 2); // 48 KiB
    ushort* W2p   = (ushort*)alloc((size_t)2 * 3 * 64 * 8 * 2); // 6 KiB
    int*   gcount = (int*)alloc((size_t)NBUCK * 4);
    uint32* h2b   = (uint32*)h1;  // h1 dead after agg96; 3.2 MB fits in 9.6 MB

    const int nbB1    = (MEDGES + 2047) / 2048;  // 416
    const int nbGemm  = (NNODES + 63) / 64;      // 782
    const int nbAggP  = NNODES / 8;              // 6250 (exact)

    packw_kernel<<<13, 256, 0, stream>>>(W1, W2, W1p, W2p, gcount);
    bucket1_kernel<<<nbB1, 256, 0, stream>>>(ei, gcount, staging);
    bucket2_kernel<<<NBUCK, 256, 0, stream>>>(staging, gcount, rowptr, esrc);

    // layer 1
    gemm1_kernel<<<nbGemm, 256, 0, stream>>>(x, W1p, a1s, a1d, h1, as1, ad1);
    agg96_kernel<<<nbAggP, 256, 0, stream>>>(h1, as1, ad1, b1, rowptr, esrc, out1b);

    // layer 2
    gemm2_kernel<<<nbGemm, 256, 0, stream>>>(out1b, W2p, a2s, a2d, h2b, as2, ad2);
    agg32_kernel<<<nbAggP, 256, 0, stream>>>(h2b, as2, ad2, b2, rowptr, esrc, out);
}